// Round 7
// baseline (126.109 us; speedup 1.0000x reference)
//
#include <hip/hip_runtime.h>
#include <hip/hip_bf16.h>

// TripletLoss N=8192, D=128. Round 9: spill fix + t-units algebra.
// Round-8 post-mortem: VGPR_Count=64 + WRITE_SIZE 9.5MB (legit ~1.3MB) =
// compiler squeezed regs to 64 for 8 waves/SIMD and spilled ~25 regs into
// the hot loop -- while the 1024-block grid caps occupancy at 16 waves/CU
// anyway. Fix: amdgpu_waves_per_eu(4,4) pins the allocator at the 128-reg
// budget (no spill, same achievable occupancy).
// New algebra: prep scales Fb by AK1=sqrt2*log2(e). Then the MFMA epilogue
// acc = -K1^2*d2/2, t = sqrt(-acc), ne = exp2(-t) (free neg modifier) --
// one fewer VALU op per pair (no K1*s mul). dist = t*ln2; finalize uses
// LN2, positives use exp2(t + C2). Everything (partial, corr) in t-units.

typedef __bf16 bf16x8 __attribute__((ext_vector_type(8)));
typedef float f32x4 __attribute__((ext_vector_type(4)));

#define NROWS 8192
#define DIM 128
#define JTILE 64
#define LDS_STRIDE 136    // 128 + 8 bf16 pad: 272B = 17 x 16B units (odd -> b128 conflict-free)
#define NLABELS 512
#define GCAP 64           // max rows per label (E=16, sigma~4; P(>64) ~ 1e-30)
#define MARGIN_F 0.3f
#define AK1F 2.04027892f     // sqrt2 * log2(e); Fb and x2 are pre-scaled by this
#define EPS_T 2.08137e-8f    // AK1^2 * 5e-9  (matches reference clip(d2,1e-8))
#define C2F (-43.2808512f)   // -30 * log2(e):  exp(dist-30) = exp2(t + C2)
#define LN2F 0.69314718f     // dist = t * ln2

// ---------------- kernel 1: scaled bf16 cast + row norms + label buckets ----
__global__ __launch_bounds__(256) void prep_kernel(const float* __restrict__ F,
                                                   const int* __restrict__ labels,
                                                   __hip_bfloat16* __restrict__ Fb,
                                                   float* __restrict__ x2,
                                                   int* __restrict__ gcnt,
                                                   int* __restrict__ gslot) {
    const int tid = threadIdx.x;
    const int wave = tid >> 6, lane = tid & 63;
    const int row = blockIdx.x * 4 + wave;
    float2 f = ((const float2*)(F + (size_t)row * DIM))[lane];
    f.x *= AK1F; f.y *= AK1F;
    ((__hip_bfloat162*)(Fb + (size_t)row * DIM))[lane] = __float22bfloat162_rn(f);
    float ss = f.x * f.x + f.y * f.y;
#pragma unroll
    for (int m = 32; m > 0; m >>= 1) ss += __shfl_xor(ss, m, 64);
    if (lane == 0) {
        x2[row] = ss;
        const int lab = labels[row];
        int pos = atomicAdd(&gcnt[lab], 1);
        if (pos < GCAP) gslot[lab * GCAP + pos] = row;
    }
}

// ---------------- kernel 2: fused GEMM + mining, corr tail on by<=1 --------
// 128 i-rows per block: 32 per wave as 2 row-groups sharing each LDS B read.
template<bool DIAG>
__device__ __forceinline__ void tile_body(const __hip_bfloat16* __restrict__ sB,
                                          const float* __restrict__ sX2h,
                                          const bf16x8 (&a)[2][4],
                                          const float (&x2ih)[2][4],
                                          float (&nl)[2][4], float (&ns)[2][4],
                                          int lm, int quad, int ibase, int jbase) {
#pragma unroll
    for (int jt = 0; jt < 4; ++jt) {
        const int jl = jt * 16 + lm;
        const __hip_bfloat16* bp = sB + jl * LDS_STRIDE + quad * 8;
        bf16x8 b[4];
#pragma unroll
        for (int kc = 0; kc < 4; ++kc) b[kc] = *(const bf16x8*)(bp + kc * 32);
        const float xjh = sX2h[jl];
#pragma unroll
        for (int g = 0; g < 2; ++g) {
            f32x4 acc;
#pragma unroll
            for (int r = 0; r < 4; ++r) acc[r] = x2ih[g][r] + xjh;
#pragma unroll
            for (int kc = 0; kc < 4; ++kc)
                acc = __builtin_amdgcn_mfma_f32_16x16x32_bf16(a[g][kc], b[kc], acc, 0, 0, 0);
            const int djg = jbase + jl - (ibase + g * 16 + quad * 4);  // self iff == r
#pragma unroll
            for (int r = 0; r < 4; ++r) {
                float d2h = fmaxf(-acc[r], EPS_T);          // = K1^2*d2/2, clipped
                float t = __builtin_amdgcn_sqrtf(d2h);      // dist = t*ln2
                float ne = __builtin_amdgcn_exp2f(-t);      // exp(-dist)
                if (DIAG) ne = (djg == r) ? 0.f : ne;
                nl[g][r] += ne;
                ns[g][r] = fmaf(ne, t, ns[g][r]);
            }
        }
    }
}

__global__ __launch_bounds__(256)
__attribute__((amdgpu_waves_per_eu(4, 4)))
void pairs_kernel(
        const __hip_bfloat16* __restrict__ Fb,
        const float* __restrict__ x2,
        const int* __restrict__ gcnt,
        const int* __restrict__ gslot,
        float2* __restrict__ partial,
        float4* __restrict__ corr,
        int jspan) {
    __shared__ __hip_bfloat16 sB[JTILE * LDS_STRIDE];
    __shared__ float sX2h[JTILE];     // -0.5 * x2j (scaled units)

    const int tid = threadIdx.x;
    const int wave = tid >> 6;
    const int lane = tid & 63;
    const int quad = lane >> 4;
    const int lm = lane & 15;
    const int ibase = blockIdx.x * 128 + wave * 32;

    bf16x8 a[2][4];
#pragma unroll
    for (int g = 0; g < 2; ++g)
#pragma unroll
        for (int kc = 0; kc < 4; ++kc)
            a[g][kc] = *(const bf16x8*)(Fb + (size_t)(ibase + g * 16 + lm) * DIM
                                        + kc * 32 + quad * 8);

    // C/D layout: col(n)=lane&15 (j), row(m)=quad*4+r (i)
    float x2ih[2][4];
#pragma unroll
    for (int g = 0; g < 2; ++g)
#pragma unroll
        for (int r = 0; r < 4; ++r)
            x2ih[g][r] = -0.5f * x2[ibase + g * 16 + quad * 4 + r];

    float nl[2][4] = {}, ns[2][4] = {};

    const int j0 = blockIdx.y * jspan;
    const int jiters = jspan >> 6;
    const int djb0 = 2 * (int)blockIdx.x - (int)blockIdx.y * jiters;

    for (int jb = 0; jb < jiters; ++jb) {
        const int jbase = j0 + jb * JTILE;
        __syncthreads();   // protect LDS from previous iteration's readers
#pragma unroll
        for (int s = 0; s < 4; ++s) {
            int c = tid + s * 256;
            int jr = c >> 4, ck = c & 15;
            *(bf16x8*)(sB + jr * LDS_STRIDE + ck * 8) =
                *(const bf16x8*)(Fb + (size_t)(jbase + jr) * DIM + ck * 8);
        }
        if (tid < JTILE) sX2h[tid] = -0.5f * x2[jbase + tid];
        __syncthreads();

        if ((unsigned)(jb - djb0) <= 1u)
            tile_body<true >(sB, sX2h, a, x2ih, nl, ns, lm, quad, ibase, jbase);
        else
            tile_body<false>(sB, sX2h, a, x2ih, nl, ns, lm, quad, ibase, jbase);
    }

    // reduce over the 16 lanes (lm) sharing each i-row
#pragma unroll
    for (int m = 1; m < 16; m <<= 1) {
#pragma unroll
        for (int g = 0; g < 2; ++g)
#pragma unroll
            for (int r = 0; r < 4; ++r) {
                nl[g][r] += __shfl_xor(nl[g][r], m, 64);
                ns[g][r] += __shfl_xor(ns[g][r], m, 64);
            }
    }
    if (lm == 0) {
#pragma unroll
        for (int g = 0; g < 2; ++g)
#pragma unroll
            for (int r = 0; r < 4; ++r)
                partial[(size_t)blockIdx.y * NROWS + ibase + g * 16 + quad * 4 + r] =
                    make_float2(nl[g][r], ns[g][r]);
    }

    // ---- corr tail: 128 blocks (by<=1) x 4 labels, one thread per pair ----
    if (blockIdx.y > 1) return;
    __syncthreads();                       // done with sB as B-tile
    float* sAcc = (float*)sB;              // overlay: 4 x GCAP floats
    float* plA = sAcc;
    float* psA = sAcc + GCAP;
    float* nlA = sAcc + 2 * GCAP;
    float* nsA = sAcc + 3 * GCAP;
    const int cid = (int)blockIdx.x * 2 + (int)blockIdx.y;   // [0,128)

    for (int li = 0; li < NLABELS / 128; ++li) {             // 4 labels
        const int L = cid * (NLABELS / 128) + li;
        const int cnt = gcnt[L];
        const int gsz = cnt < GCAP ? cnt : GCAP;
        if (tid < GCAP) { plA[tid] = 0.f; psA[tid] = 0.f; nlA[tid] = 0.f; nsA[tid] = 0.f; }
        __syncthreads();
        const int npair = gsz * gsz;
        for (int p = tid; p < npair; p += 256) {
            const int aI = p / gsz, bI = p - aI * gsz;
            if (aI != bI) {
                const int ia = gslot[L * GCAP + aI];
                const int ib = gslot[L * GCAP + bI];
                const bf16x8* pa = (const bf16x8*)(Fb + (size_t)ia * DIM);
                const bf16x8* pb = (const bf16x8*)(Fb + (size_t)ib * DIM);
                float dot = 0.f;
#pragma unroll 4
                for (int u = 0; u < 16; ++u) {
                    bf16x8 va = pa[u], vb = pb[u];
#pragma unroll
                    for (int e = 0; e < 8; ++e)
                        dot = fmaf((float)va[e], (float)vb[e], dot);
                }
                float d2h = fmaxf(0.5f * (x2[ia] + x2[ib]) - dot, EPS_T);
                float t = __builtin_amdgcn_sqrtf(d2h);
                float ne = __builtin_amdgcn_exp2f(-t);
                float pe = __builtin_amdgcn_exp2f(t + C2F);
                unsafeAtomicAdd(&nlA[aI], ne);
                unsafeAtomicAdd(&nsA[aI], ne * t);
                unsafeAtomicAdd(&plA[aI], pe);
                unsafeAtomicAdd(&psA[aI], pe * t);
            }
        }
        __syncthreads();
        if (tid < gsz)
            corr[gslot[L * GCAP + tid]] =
                make_float4(plA[tid], psA[tid], -nlA[tid], -nsA[tid]);
        __syncthreads();                   // before reusing sAcc for next label
    }
}

// ---------------- kernel 3: per-row loss, reduce, final divide -------------
__global__ __launch_bounds__(256) void finalize_kernel(const float2* __restrict__ partial,
                                                       const float4* __restrict__ corr,
                                                       float* __restrict__ gstat,
                                                       float* __restrict__ out,
                                                       int jsplit) {
    const int row = blockIdx.x * 256 + threadIdx.x;
    float4 c = corr[row];
    float nl = c.z, ns = c.w;    // negative corrections (subtract same-label mass)
    for (int s = 0; s < jsplit; ++s) {
        float2 p = partial[(size_t)s * NROWS + row];
        nl += p.x; ns += p.y;
    }
    float sum = 0.f, cnt = 0.f;
    if (c.x > 0.f && nl > 0.f) {
        float x = fmaf(LN2F, c.y / c.x - ns / nl, MARGIN_F);   // wp - wn + margin
        sum = fmaxf(x, 0.f) + log1pf(__expf(-fabsf(x)));       // stable softplus
        cnt = 1.f;
    }
#pragma unroll
    for (int m = 32; m > 0; m >>= 1) {
        sum += __shfl_xor(sum, m, 64);
        cnt += __shfl_xor(cnt, m, 64);
    }
    __shared__ float sS[4], sC[4];
    const int wave = threadIdx.x >> 6, lane = threadIdx.x & 63;
    if (lane == 0) { sS[wave] = sum; sC[wave] = cnt; }
    __syncthreads();
    if (threadIdx.x == 0) {
        unsafeAtomicAdd(&gstat[0], sS[0] + sS[1] + sS[2] + sS[3]);
        unsafeAtomicAdd(&gstat[1], sC[0] + sC[1] + sC[2] + sC[3]);
        __threadfence();
        unsigned t = atomicAdd((unsigned int*)(gstat + 2), 1u);
        if (t == (unsigned)(gridDim.x - 1)) {
            float s2 = unsafeAtomicAdd(&gstat[0], 0.f);   // L2 reads
            float c2 = unsafeAtomicAdd(&gstat[1], 0.f);
            out[0] = s2 / fmaxf(c2, 1.f);
        }
    }
}

extern "C" void kernel_launch(void* const* d_in, const int* in_sizes, int n_in,
                              void* d_out, int out_size, void* d_ws, size_t ws_size,
                              hipStream_t stream) {
    const float* F = (const float*)d_in[0];
    const int* labels = (const int*)d_in[1];
    float* out = (float*)d_out;

    char* ws = (char*)d_ws;
    __hip_bfloat16* Fb = (__hip_bfloat16*)ws;                        // 2 MB
    size_t off = (size_t)NROWS * DIM * 2;
    float* x2 = (float*)(ws + off);   off += (size_t)NROWS * 4;      // 32 KB
    float4* corr = (float4*)(ws + off); off += (size_t)NROWS * 16;   // 128 KB
    int* gcnt = (int*)(ws + off);     off += (size_t)NLABELS * 4;    // 2 KB
    float* gstat = (float*)(ws + off); off += 16;                    // 16 B
    int* gslot = (int*)(ws + off);    off += (size_t)NLABELS * GCAP * 4;  // 128 KB

    int jsplit = 16;
    while (jsplit > 2 && off + (size_t)jsplit * NROWS * 8 > ws_size) jsplit >>= 1;
    float2* partial = (float2*)(ws + off);

    // zero gcnt (512 ints) + gstat (4 floats) — contiguous region
    hipMemsetAsync(gcnt, 0, (size_t)NLABELS * 4 + 16, stream);
    prep_kernel<<<NROWS / 4, 256, 0, stream>>>(F, labels, Fb, x2, gcnt, gslot);
    pairs_kernel<<<dim3(NROWS / 128, jsplit), 256, 0, stream>>>(
        Fb, x2, gcnt, gslot, partial, corr, NROWS / jsplit);
    finalize_kernel<<<NROWS / 256, 256, 0, stream>>>(partial, corr, gstat, out, jsplit);
}

// Round 8
// 115.790 us; speedup vs baseline: 1.0891x; 1.0891x over previous
//
#include <hip/hip_runtime.h>
#include <hip/hip_bf16.h>

// TripletLoss N=8192, D=128. Round 10: spill-proof 1-row-group waves.
// Round-9 post-mortem: gfx950 splits the per-wave register budget ~50/50
// arch-VGPR/AGPR when MFMA is present -- (256,4) => only ~64 arch regs.
// The 2-row-group working set (~90 arch) spilled in EVERY round (excess
// WRITE_SIZE 8-24MB). Fix: 1 row-group/wave (a[4]=16 + nl/ns=8 + x2ih=4 +
// b[4]=16 + addr ~10 = ~56 <= 64) at (256,4): zero spill by construction.
// Grid 128x16 = 2048 blocks (4+ blocks/CU). corr is spread over 512 blocks
// (by<4, one label each) and runs BEFORE the j-loop: no serial tail.
//
// t-units algebra (round 9): Fb,x2 pre-scaled by AK1=sqrt2*log2(e) so
// acc = -AK1^2*d2/2, t = sqrt(-acc), exp(-dist) = exp2(-t) (free neg
// modifier), dist = t*ln2. Positives: exp(dist-30) = exp2(t + C2).

typedef __bf16 bf16x8 __attribute__((ext_vector_type(8)));
typedef float f32x4 __attribute__((ext_vector_type(4)));

#define NROWS 8192
#define DIM 128
#define JTILE 64
#define LDS_STRIDE 136    // 128 + 8 bf16 pad: 272B = 17 x 16B units (odd -> b128 conflict-free)
#define NLABELS 512
#define GCAP 64           // max rows per label (E=16, sigma~4; P(>64) ~ 1e-30)
#define MARGIN_F 0.3f
#define AK1F 2.04027892f     // sqrt2 * log2(e); Fb and x2 are pre-scaled by this
#define EPS_T 2.08137e-8f    // AK1^2 * 5e-9  (matches reference clip(d2,1e-8))
#define C2F (-43.2808512f)   // -30 * log2(e):  exp(dist-30) = exp2(t + C2)
#define LN2F 0.69314718f     // dist = t * ln2

// ---------------- kernel 1: scaled bf16 cast + row norms + label buckets ----
__global__ __launch_bounds__(256) void prep_kernel(const float* __restrict__ F,
                                                   const int* __restrict__ labels,
                                                   __hip_bfloat16* __restrict__ Fb,
                                                   float* __restrict__ x2,
                                                   int* __restrict__ gcnt,
                                                   int* __restrict__ gslot) {
    const int tid = threadIdx.x;
    const int wave = tid >> 6, lane = tid & 63;
    const int row = blockIdx.x * 4 + wave;
    float2 f = ((const float2*)(F + (size_t)row * DIM))[lane];
    f.x *= AK1F; f.y *= AK1F;
    ((__hip_bfloat162*)(Fb + (size_t)row * DIM))[lane] = __float22bfloat162_rn(f);
    float ss = f.x * f.x + f.y * f.y;
#pragma unroll
    for (int m = 32; m > 0; m >>= 1) ss += __shfl_xor(ss, m, 64);
    if (lane == 0) {
        x2[row] = ss;
        const int lab = labels[row];
        int pos = atomicAdd(&gcnt[lab], 1);
        if (pos < GCAP) gslot[lab * GCAP + pos] = row;
    }
}

// ---------------- kernel 2: fused GEMM + mining; corr head on by<4 ---------
// 64 i-rows per block: 16 per wave, single row-group (spill-proof reg set).
template<bool DIAG>
__device__ __forceinline__ void tile_body(const __hip_bfloat16* __restrict__ sB,
                                          const float* __restrict__ sX2h,
                                          const bf16x8 (&a)[4],
                                          const float (&x2ih)[4],
                                          float (&nl4)[4], float (&ns4)[4],
                                          int lm, int quad, int ig0, int jbase) {
#pragma unroll
    for (int jt = 0; jt < 4; ++jt) {
        const int jl = jt * 16 + lm;
        const __hip_bfloat16* bp = sB + jl * LDS_STRIDE + quad * 8;
        const float xjh = sX2h[jl];
        f32x4 acc;
#pragma unroll
        for (int r = 0; r < 4; ++r) acc[r] = x2ih[r] + xjh;
#pragma unroll
        for (int kc = 0; kc < 4; ++kc) {
            bf16x8 b = *(const bf16x8*)(bp + kc * 32);
            acc = __builtin_amdgcn_mfma_f32_16x16x32_bf16(a[kc], b, acc, 0, 0, 0);
        }
        const int dj = jbase + jl - ig0;   // self-pair iff dj == r
#pragma unroll
        for (int r = 0; r < 4; ++r) {
            float d2h = fmaxf(-acc[r], EPS_T);          // = AK1^2*d2/2, clipped
            float t = __builtin_amdgcn_sqrtf(d2h);      // dist = t*ln2
            float ne = __builtin_amdgcn_exp2f(-t);      // exp(-dist)
            if (DIAG) ne = (dj == r) ? 0.f : ne;
            nl4[r] += ne;
            ns4[r] = fmaf(ne, t, ns4[r]);
        }
    }
}

__global__ __launch_bounds__(256, 4) void pairs_kernel(
        const __hip_bfloat16* __restrict__ Fb,
        const float* __restrict__ x2,
        const int* __restrict__ gcnt,
        const int* __restrict__ gslot,
        float2* __restrict__ partial,
        float4* __restrict__ corr,
        int jspan) {
    __shared__ __hip_bfloat16 sB[JTILE * LDS_STRIDE];
    __shared__ float sX2h[JTILE];     // -0.5 * x2j (t-units)

    const int tid = threadIdx.x;

    // ---- corr head: 512 blocks (by<4) handle one label each, BEFORE the
    // j-loop (uses only Fb/x2/buckets; sB overlay is safe pre-staging).
    if (blockIdx.y < 4) {
        const int L = (int)blockIdx.y * 128 + (int)blockIdx.x;
        float* sAcc = (float*)sB;          // overlay: 4 x GCAP floats
        float* plA = sAcc;
        float* psA = sAcc + GCAP;
        float* nlA = sAcc + 2 * GCAP;
        float* nsA = sAcc + 3 * GCAP;
        const int cnt = gcnt[L];
        const int gsz = cnt < GCAP ? cnt : GCAP;
        if (gsz > 0) {
            if (tid < GCAP) { plA[tid] = 0.f; psA[tid] = 0.f; nlA[tid] = 0.f; nsA[tid] = 0.f; }
            __syncthreads();
            const int npair = gsz * gsz;
            for (int p = tid; p < npair; p += 256) {
                const int aI = p / gsz, bI = p - aI * gsz;
                if (aI != bI) {
                    const int ia = gslot[L * GCAP + aI];
                    const int ib = gslot[L * GCAP + bI];
                    const bf16x8* pa = (const bf16x8*)(Fb + (size_t)ia * DIM);
                    const bf16x8* pb = (const bf16x8*)(Fb + (size_t)ib * DIM);
                    float dot = 0.f;
#pragma unroll 4
                    for (int u = 0; u < 16; ++u) {
                        bf16x8 va = pa[u], vb = pb[u];
#pragma unroll
                        for (int e = 0; e < 8; ++e)
                            dot = fmaf((float)va[e], (float)vb[e], dot);
                    }
                    float d2h = fmaxf(0.5f * (x2[ia] + x2[ib]) - dot, EPS_T);
                    float t = __builtin_amdgcn_sqrtf(d2h);
                    float ne = __builtin_amdgcn_exp2f(-t);
                    float pe = __builtin_amdgcn_exp2f(t + C2F);
                    unsafeAtomicAdd(&nlA[aI], ne);
                    unsafeAtomicAdd(&nsA[aI], ne * t);
                    unsafeAtomicAdd(&plA[aI], pe);
                    unsafeAtomicAdd(&psA[aI], pe * t);
                }
            }
            __syncthreads();
            if (tid < gsz)
                corr[gslot[L * GCAP + tid]] =
                    make_float4(plA[tid], psA[tid], -nlA[tid], -nsA[tid]);
        }
        // j-loop's first __syncthreads() protects sB reuse
    }

    const int wave = tid >> 6;
    const int lane = tid & 63;
    const int quad = lane >> 4;
    const int lm = lane & 15;
    const int rbase = blockIdx.x * 64 + wave * 16;

    // A fragments (16 rows x K=128), kept for the whole j loop.
    bf16x8 a[4];
#pragma unroll
    for (int kc = 0; kc < 4; ++kc)
        a[kc] = *(const bf16x8*)(Fb + (size_t)(rbase + lm) * DIM + kc * 32 + quad * 8);

    // C/D layout: col(n)=lane&15 (j), row(m)=quad*4+r (i)
    const int ig0 = rbase + quad * 4;
    float x2ih[4];
#pragma unroll
    for (int r = 0; r < 4; ++r) x2ih[r] = -0.5f * x2[ig0 + r];

    float nl4[4] = {0,0,0,0}, ns4[4] = {0,0,0,0};

    const int j0 = blockIdx.y * jspan;
    const int jiters = jspan >> 6;
    const int djb = (int)blockIdx.x - (int)blockIdx.y * jiters;  // diagonal jb

    for (int jb = 0; jb < jiters; ++jb) {
        const int jbase = j0 + jb * JTILE;
        __syncthreads();   // protect LDS from previous readers (incl. corr head)
#pragma unroll
        for (int s = 0; s < 4; ++s) {
            int c = tid + s * 256;
            int jr = c >> 4, ck = c & 15;
            *(bf16x8*)(sB + jr * LDS_STRIDE + ck * 8) =
                *(const bf16x8*)(Fb + (size_t)(jbase + jr) * DIM + ck * 8);
        }
        if (tid < JTILE) sX2h[tid] = -0.5f * x2[jbase + tid];
        __syncthreads();

        if (jb == djb)
            tile_body<true >(sB, sX2h, a, x2ih, nl4, ns4, lm, quad, ig0, jbase);
        else
            tile_body<false>(sB, sX2h, a, x2ih, nl4, ns4, lm, quad, ig0, jbase);
    }

    // reduce over the 16 lanes (lm) sharing each i-row
#pragma unroll
    for (int m = 1; m < 16; m <<= 1) {
#pragma unroll
        for (int r = 0; r < 4; ++r) {
            nl4[r] += __shfl_xor(nl4[r], m, 64);
            ns4[r] += __shfl_xor(ns4[r], m, 64);
        }
    }
    if (lm == 0) {
#pragma unroll
        for (int r = 0; r < 4; ++r)
            partial[(size_t)blockIdx.y * NROWS + ig0 + r] =
                make_float2(nl4[r], ns4[r]);
    }
}

// ---------------- kernel 3: per-row loss, reduce, final divide -------------
__global__ __launch_bounds__(256) void finalize_kernel(const float2* __restrict__ partial,
                                                       const float4* __restrict__ corr,
                                                       float* __restrict__ gstat,
                                                       float* __restrict__ out,
                                                       int jsplit) {
    const int row = blockIdx.x * 256 + threadIdx.x;
    float4 c = corr[row];
    float nl = c.z, ns = c.w;    // negative corrections (subtract same-label mass)
    for (int s = 0; s < jsplit; ++s) {
        float2 p = partial[(size_t)s * NROWS + row];
        nl += p.x; ns += p.y;
    }
    float sum = 0.f, cnt = 0.f;
    if (c.x > 0.f && nl > 0.f) {
        float x = fmaf(LN2F, c.y / c.x - ns / nl, MARGIN_F);   // wp - wn + margin
        sum = fmaxf(x, 0.f) + log1pf(__expf(-fabsf(x)));       // stable softplus
        cnt = 1.f;
    }
#pragma unroll
    for (int m = 32; m > 0; m >>= 1) {
        sum += __shfl_xor(sum, m, 64);
        cnt += __shfl_xor(cnt, m, 64);
    }
    __shared__ float sS[4], sC[4];
    const int wave = threadIdx.x >> 6, lane = threadIdx.x & 63;
    if (lane == 0) { sS[wave] = sum; sC[wave] = cnt; }
    __syncthreads();
    if (threadIdx.x == 0) {
        unsafeAtomicAdd(&gstat[0], sS[0] + sS[1] + sS[2] + sS[3]);
        unsafeAtomicAdd(&gstat[1], sC[0] + sC[1] + sC[2] + sC[3]);
        __threadfence();
        unsigned t = atomicAdd((unsigned int*)(gstat + 2), 1u);
        if (t == (unsigned)(gridDim.x - 1)) {
            float s2 = unsafeAtomicAdd(&gstat[0], 0.f);   // L2 reads
            float c2 = unsafeAtomicAdd(&gstat[1], 0.f);
            out[0] = s2 / fmaxf(c2, 1.f);
        }
    }
}

extern "C" void kernel_launch(void* const* d_in, const int* in_sizes, int n_in,
                              void* d_out, int out_size, void* d_ws, size_t ws_size,
                              hipStream_t stream) {
    const float* F = (const float*)d_in[0];
    const int* labels = (const int*)d_in[1];
    float* out = (float*)d_out;

    char* ws = (char*)d_ws;
    __hip_bfloat16* Fb = (__hip_bfloat16*)ws;                        // 2 MB
    size_t off = (size_t)NROWS * DIM * 2;
    float* x2 = (float*)(ws + off);   off += (size_t)NROWS * 4;      // 32 KB
    float4* corr = (float4*)(ws + off); off += (size_t)NROWS * 16;   // 128 KB
    int* gcnt = (int*)(ws + off);     off += (size_t)NLABELS * 4;    // 2 KB
    float* gstat = (float*)(ws + off); off += 16;                    // 16 B
    int* gslot = (int*)(ws + off);    off += (size_t)NLABELS * GCAP * 4;  // 128 KB

    int jsplit = 16;
    while (jsplit > 4 && off + (size_t)jsplit * NROWS * 8 > ws_size) jsplit >>= 1;
    float2* partial = (float2*)(ws + off);

    // zero gcnt (512 ints) + gstat (4 floats) — contiguous region
    hipMemsetAsync(gcnt, 0, (size_t)NLABELS * 4 + 16, stream);
    prep_kernel<<<NROWS / 4, 256, 0, stream>>>(F, labels, Fb, x2, gcnt, gslot);
    pairs_kernel<<<dim3(NROWS / 64, jsplit), 256, 0, stream>>>(
        Fb, x2, gcnt, gslot, partial, corr, NROWS / jsplit);
    finalize_kernel<<<NROWS / 256, 256, 0, stream>>>(partial, corr, gstat, out, jsplit);
}